// Round 9
// baseline (398.399 us; speedup 1.0000x reference)
//
#include <hip/hip_runtime.h>
#include <math.h>

typedef __attribute__((ext_vector_type(8))) short bf16x8;
typedef __attribute__((ext_vector_type(4))) float f32x4;

__device__ inline unsigned short f2bf(float f) {
  union { float f; unsigned u; } x; x.f = f;
  unsigned r = x.u + 0x7FFF + ((x.u >> 16) & 1);
  return (unsigned short)(r >> 16);
}
__device__ inline float bf2f(unsigned short b) {
  union { unsigned u; float f; } x; x.u = ((unsigned)b) << 16;
  return x.f;
}

// ---------------- CSR build ----------------

__global__ void convert_kernel(const void* edges, int E, int N,
                               int* __restrict__ src32, int* __restrict__ dst32,
                               int* __restrict__ counts) {
  int i = blockIdx.x * blockDim.x + threadIdx.x;
  int tot = E + N;
  if (i >= tot) return;
  int s, d;
  if (i < E) {
    const long long* q = (const long long*)edges;
    bool i64 = true;
#pragma unroll
    for (int k = 0; k < 8; ++k) {
      long long v = q[k];
      if (v < 0 || v >= (long long)N) i64 = false;
    }
    if (i64) {
      s = (int)q[i];
      d = (int)q[E + i];
    } else {
      s = ((const int*)edges)[i];
      d = ((const int*)edges)[E + i];
    }
  } else {  // self loops
    s = d = i - E;
  }
  src32[i] = s;
  dst32[i] = d;
  atomicAdd(&counts[d], 1);
}

// ---- 3-phase parallel exclusive scan over counts[N] (1024 elems/block) ----

__global__ __launch_bounds__(256) void scan_partial(const int* __restrict__ counts,
                                                    int* __restrict__ bsum, int n) {
  int t = threadIdx.x;
  int base = blockIdx.x * 1024 + t * 4;
  int s = 0;
#pragma unroll
  for (int k = 0; k < 4; ++k) {
    int i = base + k;
    if (i < n) s += counts[i];
  }
#pragma unroll
  for (int off = 32; off; off >>= 1) s += __shfl_xor(s, off);
  __shared__ int red[4];
  if ((t & 63) == 0) red[t >> 6] = s;
  __syncthreads();
  if (t == 0) bsum[blockIdx.x] = red[0] + red[1] + red[2] + red[3];
}

__global__ __launch_bounds__(256) void scan_bsum(const int* __restrict__ bsum,
                                                 int* __restrict__ ebsum,
                                                 int* __restrict__ rowptr, int nblk, int n) {
  __shared__ int sh[256];
  int t = threadIdx.x;
  int v = (t < nblk) ? bsum[t] : 0;
  sh[t] = v;
  __syncthreads();
  for (int off = 1; off < 256; off <<= 1) {
    int u = (t >= off) ? sh[t - off] : 0;
    __syncthreads();
    sh[t] += u;
    __syncthreads();
  }
  if (t < nblk) ebsum[t] = sh[t] - v;
  if (t == nblk - 1) rowptr[n] = sh[t];
}

__global__ __launch_bounds__(256) void scan_final(const int* __restrict__ counts,
                                                  const int* __restrict__ ebsum,
                                                  int* __restrict__ rowptr,
                                                  int* __restrict__ cursor, int n) {
  int t = threadIdx.x;
  int lane = t & 63;
  int wv = t >> 6;
  int base = blockIdx.x * 1024 + t * 4;
  int c[4];
  int ts = 0;
#pragma unroll
  for (int k = 0; k < 4; ++k) {
    int i = base + k;
    c[k] = (i < n) ? counts[i] : 0;
    ts += c[k];
  }
  int ws = ts;
  for (int off = 1; off < 64; off <<= 1) {
    int u = __shfl_up(ws, off);
    if (lane >= off) ws += u;
  }
  __shared__ int wtot[4];
  if (lane == 63) wtot[wv] = ws;
  __syncthreads();
  int woff = 0;
  for (int k = 0; k < 4; ++k)
    if (k < wv) woff += wtot[k];
  int run = ebsum[blockIdx.x] + woff + (ws - ts);
#pragma unroll
  for (int k = 0; k < 4; ++k) {
    int i = base + k;
    if (i < n) {
      rowptr[i] = run;
      cursor[i] = run;
    }
    run += c[k];
  }
}

__global__ void scatter_kernel(const int* __restrict__ src32, const int* __restrict__ dst32,
                               int* __restrict__ cursor, int* __restrict__ csr_src, int tot) {
  int i = blockIdx.x * blockDim.x + threadIdx.x;
  if (i >= tot) return;
  int d = dst32[i];
  int slot = atomicAdd(&cursor[d], 1);
  csr_src[slot] = src32[i];
}

// ---------------- fused dtype conversion (x + all 4 weights) ----------------

__global__ void cvt_all(const float* __restrict__ x,
                        const float* __restrict__ W1, const float* __restrict__ Wres1,
                        const float* __restrict__ W2, const float* __restrict__ Wres2,
                        unsigned short* __restrict__ x16,
                        unsigned short* __restrict__ w1t, unsigned short* __restrict__ wres1t,
                        unsigned short* __restrict__ w2t, unsigned short* __restrict__ wres2t,
                        int N, int Mpad) {
  int tid = blockIdx.x * blockDim.x + threadIdx.x;
  int xcnt = Mpad * 32;
  if (tid < xcnt) {
    int row = tid >> 5;
    int q = (tid & 31) << 2;
    unsigned short o0 = 0, o1 = 0, o2 = 0, o3 = 0;
    if (row < N) {
      float4 v = *(const float4*)(x + (size_t)row * 128 + q);
      o0 = f2bf(v.x); o1 = f2bf(v.y); o2 = f2bf(v.z); o3 = f2bf(v.w);
    }
    unsigned short* p = x16 + (size_t)row * 128 + q;
    p[0] = o0; p[1] = o1; p[2] = o2; p[3] = o3;
    return;
  }
  int t2 = tid - xcnt;
  const float* W;
  unsigned short* Wt;
  int C, loc;
  if (t2 < 16384) { W = W1; Wt = w1t; C = 128; loc = t2; }
  else if (t2 < 32768) { W = Wres1; Wt = wres1t; C = 128; loc = t2 - 16384; }
  else if (t2 < 65536) { W = W2; Wt = w2t; C = 256; loc = t2 - 32768; }
  else if (t2 < 98304) { W = Wres2; Wt = wres2t; C = 256; loc = t2 - 65536; }
  else return;
  int c = loc >> 7;
  int k = loc & 127;
  Wt[(size_t)c * 128 + k] = f2bf(W[(size_t)k * C + c]);
}

// ------- dual bf16 MFMA GEMM + fused attention-scalar epilogue -------
// One pass over A computes H = A@Wh^T (bf16 out, no bias) AND R = A@Wr^T + bias
// (bf16 out). Epilogue also accumulates as_[row] += H-row . a_src,
// ad_[row] += H-row . a_dst via 16-lane reduce + atomicAdd (as_/ad_ pre-zeroed).

__global__ __launch_bounds__(256) void gemm_dual(
    const unsigned short* __restrict__ A,
    const unsigned short* __restrict__ Bh, const unsigned short* __restrict__ Br,
    unsigned short* __restrict__ Hout, unsigned short* __restrict__ Rout,
    const float* __restrict__ bias,
    const float* __restrict__ a_src, const float* __restrict__ a_dst,
    float* __restrict__ as_, float* __restrict__ ad_,
    int Nrows, int Ctot) {
  int l = threadIdx.x & 63;
  int w = threadIdx.x >> 6;
  int row_w = blockIdx.x * 128 + (w & 1) * 64;
  int col_w = blockIdx.y * 128 + (w >> 1) * 64;
  int lo = l & 15, hi = l >> 4;
  f32x4 ah[4][4], ar[4][4];
#pragma unroll
  for (int i = 0; i < 4; ++i)
#pragma unroll
    for (int j = 0; j < 4; ++j) {
      ah[i][j] = (f32x4){0.f, 0.f, 0.f, 0.f};
      ar[i][j] = (f32x4){0.f, 0.f, 0.f, 0.f};
    }

  const unsigned short* Ap = A + (size_t)(row_w + lo) * 128 + hi * 8;
  const unsigned short* Bhp = Bh + (size_t)(col_w + lo) * 128 + hi * 8;
  const unsigned short* Brp = Br + (size_t)(col_w + lo) * 128 + hi * 8;
#pragma unroll
  for (int kk = 0; kk < 4; ++kk) {
    bf16x8 a[4], bh[4], br[4];
#pragma unroll
    for (int f = 0; f < 4; ++f) {
      a[f] = *(const bf16x8*)(Ap + (size_t)f * 16 * 128 + kk * 32);
      bh[f] = *(const bf16x8*)(Bhp + (size_t)f * 16 * 128 + kk * 32);
      br[f] = *(const bf16x8*)(Brp + (size_t)f * 16 * 128 + kk * 32);
    }
#pragma unroll
    for (int fr = 0; fr < 4; ++fr)
#pragma unroll
      for (int fc = 0; fc < 4; ++fc) {
        ah[fr][fc] = __builtin_amdgcn_mfma_f32_16x16x32_bf16(a[fr], bh[fc], ah[fr][fc], 0, 0, 0);
        ar[fr][fc] = __builtin_amdgcn_mfma_f32_16x16x32_bf16(a[fr], br[fc], ar[fr][fc], 0, 0, 0);
      }
  }
  // D layout: col = lane&15, row = (lane>>4)*4 + reg   [m89-verified]
  float wsrc[4], wdst[4], wb[4];
#pragma unroll
  for (int fc = 0; fc < 4; ++fc) {
    int col = col_w + fc * 16 + lo;
    wsrc[fc] = a_src[col];
    wdst[fc] = a_dst[col];
    wb[fc] = bias[col];
  }
#pragma unroll
  for (int fr = 0; fr < 4; ++fr) {
#pragma unroll
    for (int r = 0; r < 4; ++r) {
      int row = row_w + fr * 16 + hi * 4 + r;
      if (row < Nrows) {
        float s1 = 0.f, s2 = 0.f;
#pragma unroll
        for (int fc = 0; fc < 4; ++fc) {
          int col = col_w + fc * 16 + lo;
          float vh = ah[fr][fc][r];
          Hout[(size_t)row * Ctot + col] = f2bf(vh);
          s1 = fmaf(vh, wsrc[fc], s1);
          s2 = fmaf(vh, wdst[fc], s2);
          Rout[(size_t)row * Ctot + col] = f2bf(ar[fr][fc][r] + wb[fc]);
        }
#pragma unroll
        for (int off = 8; off; off >>= 1) {
          s1 += __shfl_xor(s1, off);
          s2 += __shfl_xor(s2, off);
        }
        if (lo == 0) {
          atomicAdd(&as_[row], s1);
          atomicAdd(&ad_[row], s2);
        }
      }
    }
  }
}

// ---------------- per-dst online-softmax aggregation ----------------
// One wave per dst node; 8x-unrolled gather for memory-level parallelism.

template <int C, bool L1>
__global__ __launch_bounds__(256) void aggregate_kernel(
    const unsigned short* __restrict__ h, unsigned short* __restrict__ res,
    float* __restrict__ outf,
    const float* __restrict__ as_, const float* __restrict__ ad_,
    const int* __restrict__ rowptr, const int* __restrict__ csr_src, int N) {
  const int FPL = C / 64;
  int wid = blockIdx.x * 4 + (threadIdx.x >> 6);
  int lane = threadIdx.x & 63;
  if (wid >= N) return;
  int base = rowptr[wid];
  int deg = rowptr[wid + 1] - base;
  float adn = ad_[wid];
  float m = -1e30f, ssum = 0.f;
  float acc[FPL];
#pragma unroll
  for (int c = 0; c < FPL; ++c) acc[c] = 0.f;
  for (int b0 = 0; b0 < deg; b0 += 64) {
    int idx = b0 + lane;
    int s = 0;
    float logit = -1e30f;
    if (idx < deg) {
      s = csr_src[base + idx];
      float tt = as_[s] + adn;
      logit = tt > 0.f ? tt : 0.2f * tt;  // LeakyReLU 0.2
    }
    float cm = logit;
#pragma unroll
    for (int off = 32; off; off >>= 1) cm = fmaxf(cm, __shfl_xor(cm, off));
    float mnew = fmaxf(m, cm);
    float scale = __expf(m - mnew);
    ssum *= scale;
#pragma unroll
    for (int c = 0; c < FPL; ++c) acc[c] *= scale;
    float p = (idx < deg) ? __expf(logit - mnew) : 0.f;
    float ps = p;
#pragma unroll
    for (int off = 32; off; off >>= 1) ps += __shfl_xor(ps, off);
    ssum += ps;
    int cnt = min(64, deg - b0);
    int j = 0;
    for (; j + 8 <= cnt; j += 8) {
      float pj[8];
      int sj[8];
#pragma unroll
      for (int u = 0; u < 8; ++u) {
        pj[u] = __shfl(p, j + u);
        sj[u] = __shfl(s, j + u);
      }
      if (FPL == 2) {
        ushort2 v[8];
#pragma unroll
        for (int u = 0; u < 8; ++u)
          v[u] = *(const ushort2*)(h + (size_t)sj[u] * C + FPL * lane);
#pragma unroll
        for (int u = 0; u < 8; ++u) {
          acc[0] = fmaf(pj[u], bf2f(v[u].x), acc[0]);
          acc[1] = fmaf(pj[u], bf2f(v[u].y), acc[1]);
        }
      } else {
        ushort4 v[8];
#pragma unroll
        for (int u = 0; u < 8; ++u)
          v[u] = *(const ushort4*)(h + (size_t)sj[u] * C + FPL * lane);
#pragma unroll
        for (int u = 0; u < 8; ++u) {
          acc[0] = fmaf(pj[u], bf2f(v[u].x), acc[0]);
          acc[1] = fmaf(pj[u], bf2f(v[u].y), acc[1]);
          acc[2] = fmaf(pj[u], bf2f(v[u].z), acc[2]);
          acc[3] = fmaf(pj[u], bf2f(v[u].w), acc[3]);
        }
      }
    }
    for (; j < cnt; ++j) {
      float pj = __shfl(p, j);
      int sj = __shfl(s, j);
      const unsigned short* hs = h + (size_t)sj * C + FPL * lane;
      if (FPL == 2) {
        ushort2 hv = *(const ushort2*)hs;
        acc[0] = fmaf(pj, bf2f(hv.x), acc[0]);
        acc[1] = fmaf(pj, bf2f(hv.y), acc[1]);
      } else {
        ushort4 hv = *(const ushort4*)hs;
        acc[0] = fmaf(pj, bf2f(hv.x), acc[0]);
        acc[1] = fmaf(pj, bf2f(hv.y), acc[1]);
        acc[2] = fmaf(pj, bf2f(hv.z), acc[2]);
        acc[3] = fmaf(pj, bf2f(hv.w), acc[3]);
      }
    }
    m = mnew;
  }
  float inv = 1.f / ssum;
  size_t o = (size_t)wid * C + FPL * lane;
  if (L1) {
    unsigned short* p = res + o;
    ushort2 rv = *(const ushort2*)p;
    float v0 = fmaxf(acc[0] * inv + bf2f(rv.x), 0.f);  // relu
    float v1 = fmaxf(acc[1] * inv + bf2f(rv.y), 0.f);
    ushort2 ov; ov.x = f2bf(v0); ov.y = f2bf(v1);
    *(ushort2*)p = ov;
  } else {
    ushort4 rv = *(const ushort4*)(res + o);
    float4 ov;
    ov.x = acc[0] * inv + bf2f(rv.x);
    ov.y = acc[1] * inv + bf2f(rv.y);
    ov.z = acc[2] * inv + bf2f(rv.z);
    ov.w = acc[3] * inv + bf2f(rv.w);
    *(float4*)(outf + o) = ov;
  }
}

// ---------------- launch ----------------

extern "C" void kernel_launch(void* const* d_in, const int* in_sizes, int n_in,
                              void* d_out, int out_size, void* d_ws, size_t ws_size,
                              hipStream_t stream) {
  const float* x = (const float*)d_in[0];
  const void* edges = d_in[1];
  const float* W1 = (const float*)d_in[2];
  const float* a_src1 = (const float*)d_in[3];
  const float* a_dst1 = (const float*)d_in[4];
  const float* b1 = (const float*)d_in[5];
  const float* Wres1 = (const float*)d_in[6];
  const float* W2 = (const float*)d_in[7];
  const float* a_src2 = (const float*)d_in[8];
  const float* a_dst2 = (const float*)d_in[9];
  const float* b2 = (const float*)d_in[10];
  const float* Wres2 = (const float*)d_in[11];
  float* out = (float*)d_out;

  int N = in_sizes[0] / 128;
  int E = in_sizes[1] / 2;
  int TOT = E + N;
  int Mpad = (N + 127) & ~127;
  int nblk = (N + 1023) >> 10;

  char* w = (char*)d_ws;
  size_t off = 0;
  auto alloc = [&](size_t bytes) {
    char* p = w + off;
    off += (bytes + 255) & ~(size_t)255;
    return p;
  };
  int* counts = (int*)alloc((size_t)N * 4);
  int* cursor = (int*)alloc((size_t)N * 4);
  int* rowptr = (int*)alloc((size_t)(N + 1) * 4);
  int* bsum = (int*)alloc(1024);
  int* ebsum = (int*)alloc(1024);
  float* as_ = (float*)alloc((size_t)N * 4);
  float* ad_ = (float*)alloc((size_t)N * 4);
  int* src32 = (int*)alloc((size_t)TOT * 4);
  int* dst32 = (int*)alloc((size_t)TOT * 4);
  int* csr = (int*)alloc((size_t)TOT * 4);
  unsigned short* x16 = (unsigned short*)alloc((size_t)Mpad * 128 * 2);
  unsigned short* w1t = (unsigned short*)alloc(128 * 128 * 2);
  unsigned short* wres1t = (unsigned short*)alloc(128 * 128 * 2);
  unsigned short* w2t = (unsigned short*)alloc(256 * 128 * 2);
  unsigned short* wres2t = (unsigned short*)alloc(256 * 128 * 2);
  unsigned short* h16 = (unsigned short*)alloc((size_t)N * 256 * 2);
  unsigned short* out1 = (unsigned short*)alloc((size_t)Mpad * 128 * 2);
  unsigned short* res2 = (unsigned short*)alloc((size_t)Mpad * 256 * 2);

  hipMemsetAsync(counts, 0, (size_t)N * 4, stream);
  hipMemsetAsync(out1 + (size_t)N * 128, 0, (size_t)(Mpad - N) * 128 * 2, stream);

  int gb = (TOT + 255) / 256;
  convert_kernel<<<gb, 256, 0, stream>>>(edges, E, N, src32, dst32, counts);
  scan_partial<<<nblk, 256, 0, stream>>>(counts, bsum, N);
  scan_bsum<<<1, 256, 0, stream>>>(bsum, ebsum, rowptr, nblk, N);
  scan_final<<<nblk, 256, 0, stream>>>(counts, ebsum, rowptr, cursor, N);
  scatter_kernel<<<gb, 256, 0, stream>>>(src32, dst32, cursor, csr, TOT);

  cvt_all<<<(Mpad * 32 + 98304 + 255) / 256, 256, 0, stream>>>(
      x, W1, Wres1, W2, Wres2, x16, w1t, wres1t, w2t, wres2t, N, Mpad);

  int mt = Mpad / 128;
  int sb = (N + 3) / 4;

  // ---- layer 1 (C=128) ----
  hipMemsetAsync(as_, 0, (size_t)N * 4, stream);
  hipMemsetAsync(ad_, 0, (size_t)N * 4, stream);
  gemm_dual<<<dim3(mt, 1), 256, 0, stream>>>(x16, w1t, wres1t, h16, out1, b1,
                                             a_src1, a_dst1, as_, ad_, N, 128);
  aggregate_kernel<128, true><<<sb, 256, 0, stream>>>(h16, out1, nullptr, as_, ad_, rowptr, csr, N);

  // ---- layer 2 (C=256) ----
  hipMemsetAsync(as_, 0, (size_t)N * 4, stream);
  hipMemsetAsync(ad_, 0, (size_t)N * 4, stream);
  gemm_dual<<<dim3(mt, 2), 256, 0, stream>>>(out1, w2t, wres2t, h16, res2, b2,
                                             a_src2, a_dst2, as_, ad_, N, 256);
  aggregate_kernel<256, false><<<sb, 256, 0, stream>>>(h16, res2, out, as_, ad_, rowptr, csr, N);
}

// Round 10
// 382.933 us; speedup vs baseline: 1.0404x; 1.0404x over previous
//
#include <hip/hip_runtime.h>
#include <math.h>

typedef __attribute__((ext_vector_type(8))) short bf16x8;
typedef __attribute__((ext_vector_type(4))) float f32x4;

__device__ inline unsigned short f2bf(float f) {
  union { float f; unsigned u; } x; x.f = f;
  unsigned r = x.u + 0x7FFF + ((x.u >> 16) & 1);
  return (unsigned short)(r >> 16);
}
__device__ inline float bf2f(unsigned short b) {
  union { unsigned u; float f; } x; x.u = ((unsigned)b) << 16;
  return x.f;
}

// ---------------- CSR build ----------------

__global__ void convert_kernel(const void* edges, int E, int N,
                               int* __restrict__ src32, int* __restrict__ dst32,
                               int* __restrict__ counts) {
  int i = blockIdx.x * blockDim.x + threadIdx.x;
  int tot = E + N;
  if (i >= tot) return;
  int s, d;
  if (i < E) {
    const long long* q = (const long long*)edges;
    bool i64 = true;
#pragma unroll
    for (int k = 0; k < 8; ++k) {
      long long v = q[k];
      if (v < 0 || v >= (long long)N) i64 = false;
    }
    if (i64) {
      s = (int)q[i];
      d = (int)q[E + i];
    } else {
      s = ((const int*)edges)[i];
      d = ((const int*)edges)[E + i];
    }
  } else {  // self loops
    s = d = i - E;
  }
  src32[i] = s;
  dst32[i] = d;
  atomicAdd(&counts[d], 1);
}

// ---- 3-phase parallel exclusive scan over counts[N] (1024 elems/block) ----

__global__ __launch_bounds__(256) void scan_partial(const int* __restrict__ counts,
                                                    int* __restrict__ bsum, int n) {
  int t = threadIdx.x;
  int base = blockIdx.x * 1024 + t * 4;
  int s = 0;
#pragma unroll
  for (int k = 0; k < 4; ++k) {
    int i = base + k;
    if (i < n) s += counts[i];
  }
#pragma unroll
  for (int off = 32; off; off >>= 1) s += __shfl_xor(s, off);
  __shared__ int red[4];
  if ((t & 63) == 0) red[t >> 6] = s;
  __syncthreads();
  if (t == 0) bsum[blockIdx.x] = red[0] + red[1] + red[2] + red[3];
}

__global__ __launch_bounds__(256) void scan_bsum(const int* __restrict__ bsum,
                                                 int* __restrict__ ebsum,
                                                 int* __restrict__ rowptr, int nblk, int n) {
  __shared__ int sh[256];
  int t = threadIdx.x;
  int v = (t < nblk) ? bsum[t] : 0;
  sh[t] = v;
  __syncthreads();
  for (int off = 1; off < 256; off <<= 1) {
    int u = (t >= off) ? sh[t - off] : 0;
    __syncthreads();
    sh[t] += u;
    __syncthreads();
  }
  if (t < nblk) ebsum[t] = sh[t] - v;
  if (t == nblk - 1) rowptr[n] = sh[t];
}

__global__ __launch_bounds__(256) void scan_final(const int* __restrict__ counts,
                                                  const int* __restrict__ ebsum,
                                                  int* __restrict__ rowptr,
                                                  int* __restrict__ cursor, int n) {
  int t = threadIdx.x;
  int lane = t & 63;
  int wv = t >> 6;
  int base = blockIdx.x * 1024 + t * 4;
  int c[4];
  int ts = 0;
#pragma unroll
  for (int k = 0; k < 4; ++k) {
    int i = base + k;
    c[k] = (i < n) ? counts[i] : 0;
    ts += c[k];
  }
  int ws = ts;
  for (int off = 1; off < 64; off <<= 1) {
    int u = __shfl_up(ws, off);
    if (lane >= off) ws += u;
  }
  __shared__ int wtot[4];
  if (lane == 63) wtot[wv] = ws;
  __syncthreads();
  int woff = 0;
  for (int k = 0; k < 4; ++k)
    if (k < wv) woff += wtot[k];
  int run = ebsum[blockIdx.x] + woff + (ws - ts);
#pragma unroll
  for (int k = 0; k < 4; ++k) {
    int i = base + k;
    if (i < n) {
      rowptr[i] = run;
      cursor[i] = run;
    }
    run += c[k];
  }
}

__global__ void scatter_kernel(const int* __restrict__ src32, const int* __restrict__ dst32,
                               int* __restrict__ cursor, int* __restrict__ csr_src, int tot) {
  int i = blockIdx.x * blockDim.x + threadIdx.x;
  if (i >= tot) return;
  int d = dst32[i];
  int slot = atomicAdd(&cursor[d], 1);
  csr_src[slot] = src32[i];
}

// ---------------- fused dtype conversion (x + all 4 weights) ----------------

__global__ void cvt_all(const float* __restrict__ x,
                        const float* __restrict__ W1, const float* __restrict__ Wres1,
                        const float* __restrict__ W2, const float* __restrict__ Wres2,
                        unsigned short* __restrict__ x16,
                        unsigned short* __restrict__ w1t, unsigned short* __restrict__ wres1t,
                        unsigned short* __restrict__ w2t, unsigned short* __restrict__ wres2t,
                        int N, int Mpad) {
  int tid = blockIdx.x * blockDim.x + threadIdx.x;
  int xcnt = Mpad * 32;
  if (tid < xcnt) {
    int row = tid >> 5;
    int q = (tid & 31) << 2;
    unsigned short o0 = 0, o1 = 0, o2 = 0, o3 = 0;
    if (row < N) {
      float4 v = *(const float4*)(x + (size_t)row * 128 + q);
      o0 = f2bf(v.x); o1 = f2bf(v.y); o2 = f2bf(v.z); o3 = f2bf(v.w);
    }
    unsigned short* p = x16 + (size_t)row * 128 + q;
    p[0] = o0; p[1] = o1; p[2] = o2; p[3] = o3;
    return;
  }
  int t2 = tid - xcnt;
  const float* W;
  unsigned short* Wt;
  int C, loc;
  if (t2 < 16384) { W = W1; Wt = w1t; C = 128; loc = t2; }
  else if (t2 < 32768) { W = Wres1; Wt = wres1t; C = 128; loc = t2 - 16384; }
  else if (t2 < 65536) { W = W2; Wt = w2t; C = 256; loc = t2 - 32768; }
  else if (t2 < 98304) { W = Wres2; Wt = wres2t; C = 256; loc = t2 - 65536; }
  else return;
  int c = loc >> 7;
  int k = loc & 127;
  Wt[(size_t)c * 128 + k] = f2bf(W[(size_t)k * C + c]);
}

// ------- bf16 MFMA GEMM, LDS-staged swizzled A-tile -------
// Block: 256 thr / 4 waves, output tile 128 x 128, K = 128 one-shot.
// A-tile reg-staged into LDS with 16B-chunk XOR swizzle (chunk ^= row&7):
// staging global loads coalesced; ds_read_b128 fragments bank-balanced.
// B (weights, [Ctot][128] bf16) fragment-direct from global (L1/L2-hot).
// SCAL=1: H-gemm — store H bf16 + fused attention scalars
//         (as_[row]+=H.a_src, ad_[row]+=H.a_dst; 16-lane reduce + atomicAdd).
// SCAL=0: R-gemm — store (R + bias) bf16.

template <int SCAL>
__global__ __launch_bounds__(256) void gemm_tile(
    const unsigned short* __restrict__ A,
    const unsigned short* __restrict__ Bt,
    unsigned short* __restrict__ Cout,
    const float* __restrict__ bias,
    const float* __restrict__ a_src, const float* __restrict__ a_dst,
    float* __restrict__ as_, float* __restrict__ ad_,
    int Nrows, int Ctot) {
  __shared__ unsigned short Asw[128 * 128];  // 32KB
  int t = threadIdx.x;
  int row0 = blockIdx.x * 128;

  // stage A-tile: 2048 16B-chunks over 256 threads = 8 iters, coalesced reads
#pragma unroll
  for (int i = 0; i < 8; ++i) {
    int li = i * 256 + t;
    int r = li >> 4;       // 0..127
    int c = li & 15;       // 16B chunk within row
    bf16x8 v = *(const bf16x8*)(A + (size_t)(row0 + r) * 128 + c * 8);
    *(bf16x8*)(Asw + r * 128 + ((c ^ (r & 7)) * 8)) = v;
  }
  __syncthreads();

  int w = t >> 6;
  int l = t & 63;
  int lo = l & 15, hi = l >> 4;
  int row_w = row0 + (w & 1) * 64;
  int col_w = blockIdx.y * 128 + (w >> 1) * 64;
  int rt0 = (w & 1) * 64 + lo;

  f32x4 acc[4][4];
#pragma unroll
  for (int i = 0; i < 4; ++i)
#pragma unroll
    for (int j = 0; j < 4; ++j) acc[i][j] = (f32x4){0.f, 0.f, 0.f, 0.f};

  const unsigned short* Bp = Bt + (size_t)(col_w + lo) * 128 + hi * 8;
#pragma unroll
  for (int kk = 0; kk < 4; ++kk) {
    int blk = (kk * 4 + hi) ^ (lo & 7);  // (rt&7)==(lo&7) since rt0%16==lo
    bf16x8 a[4], b[4];
#pragma unroll
    for (int f = 0; f < 4; ++f) {
      a[f] = *(const bf16x8*)(Asw + (rt0 + f * 16) * 128 + blk * 8);
      b[f] = *(const bf16x8*)(Bp + (size_t)f * 16 * 128 + kk * 32);
    }
#pragma unroll
    for (int fr = 0; fr < 4; ++fr)
#pragma unroll
      for (int fc = 0; fc < 4; ++fc)
        acc[fr][fc] = __builtin_amdgcn_mfma_f32_16x16x32_bf16(a[fr], b[fc], acc[fr][fc], 0, 0, 0);
  }

  // D layout: col = lane&15, row = (lane>>4)*4 + reg   [m89-verified]
  float w0[4], w1[4];
#pragma unroll
  for (int fc = 0; fc < 4; ++fc) {
    int col = col_w + fc * 16 + lo;
    if (SCAL) {
      w0[fc] = a_src[col];
      w1[fc] = a_dst[col];
    } else {
      w0[fc] = bias[col];
    }
  }
#pragma unroll
  for (int fr = 0; fr < 4; ++fr) {
#pragma unroll
    for (int r = 0; r < 4; ++r) {
      int row = row_w + fr * 16 + hi * 4 + r;
      if (row < Nrows) {
        float s1 = 0.f, s2 = 0.f;
#pragma unroll
        for (int fc = 0; fc < 4; ++fc) {
          int col = col_w + fc * 16 + lo;
          float v = acc[fr][fc][r];
          if (SCAL) {
            s1 = fmaf(v, w0[fc], s1);
            s2 = fmaf(v, w1[fc], s2);
          } else {
            v += w0[fc];
          }
          Cout[(size_t)row * Ctot + col] = f2bf(v);
        }
        if (SCAL) {
#pragma unroll
          for (int off = 8; off; off >>= 1) {
            s1 += __shfl_xor(s1, off);
            s2 += __shfl_xor(s2, off);
          }
          if (lo == 0) {
            atomicAdd(&as_[row], s1);
            atomicAdd(&ad_[row], s2);
          }
        }
      }
    }
  }
}

// ---------------- per-dst online-softmax aggregation ----------------
// One wave per dst node; 8x-unrolled gather for memory-level parallelism.

template <int C, bool L1>
__global__ __launch_bounds__(256) void aggregate_kernel(
    const unsigned short* __restrict__ h, unsigned short* __restrict__ res,
    float* __restrict__ outf,
    const float* __restrict__ as_, const float* __restrict__ ad_,
    const int* __restrict__ rowptr, const int* __restrict__ csr_src, int N) {
  const int FPL = C / 64;
  int wid = blockIdx.x * 4 + (threadIdx.x >> 6);
  int lane = threadIdx.x & 63;
  if (wid >= N) return;
  int base = rowptr[wid];
  int deg = rowptr[wid + 1] - base;
  float adn = ad_[wid];
  float m = -1e30f, ssum = 0.f;
  float acc[FPL];
#pragma unroll
  for (int c = 0; c < FPL; ++c) acc[c] = 0.f;
  for (int b0 = 0; b0 < deg; b0 += 64) {
    int idx = b0 + lane;
    int s = 0;
    float logit = -1e30f;
    if (idx < deg) {
      s = csr_src[base + idx];
      float tt = as_[s] + adn;
      logit = tt > 0.f ? tt : 0.2f * tt;  // LeakyReLU 0.2
    }
    float cm = logit;
#pragma unroll
    for (int off = 32; off; off >>= 1) cm = fmaxf(cm, __shfl_xor(cm, off));
    float mnew = fmaxf(m, cm);
    float scale = __expf(m - mnew);
    ssum *= scale;
#pragma unroll
    for (int c = 0; c < FPL; ++c) acc[c] *= scale;
    float p = (idx < deg) ? __expf(logit - mnew) : 0.f;
    float ps = p;
#pragma unroll
    for (int off = 32; off; off >>= 1) ps += __shfl_xor(ps, off);
    ssum += ps;
    int cnt = min(64, deg - b0);
    int j = 0;
    for (; j + 8 <= cnt; j += 8) {
      float pj[8];
      int sj[8];
#pragma unroll
      for (int u = 0; u < 8; ++u) {
        pj[u] = __shfl(p, j + u);
        sj[u] = __shfl(s, j + u);
      }
      if (FPL == 2) {
        ushort2 v[8];
#pragma unroll
        for (int u = 0; u < 8; ++u)
          v[u] = *(const ushort2*)(h + (size_t)sj[u] * C + FPL * lane);
#pragma unroll
        for (int u = 0; u < 8; ++u) {
          acc[0] = fmaf(pj[u], bf2f(v[u].x), acc[0]);
          acc[1] = fmaf(pj[u], bf2f(v[u].y), acc[1]);
        }
      } else {
        ushort4 v[8];
#pragma unroll
        for (int u = 0; u < 8; ++u)
          v[u] = *(const ushort4*)(h + (size_t)sj[u] * C + FPL * lane);
#pragma unroll
        for (int u = 0; u < 8; ++u) {
          acc[0] = fmaf(pj[u], bf2f(v[u].x), acc[0]);
          acc[1] = fmaf(pj[u], bf2f(v[u].y), acc[1]);
          acc[2] = fmaf(pj[u], bf2f(v[u].z), acc[2]);
          acc[3] = fmaf(pj[u], bf2f(v[u].w), acc[3]);
        }
      }
    }
    for (; j < cnt; ++j) {
      float pj = __shfl(p, j);
      int sj = __shfl(s, j);
      const unsigned short* hs = h + (size_t)sj * C + FPL * lane;
      if (FPL == 2) {
        ushort2 hv = *(const ushort2*)hs;
        acc[0] = fmaf(pj, bf2f(hv.x), acc[0]);
        acc[1] = fmaf(pj, bf2f(hv.y), acc[1]);
      } else {
        ushort4 hv = *(const ushort4*)hs;
        acc[0] = fmaf(pj, bf2f(hv.x), acc[0]);
        acc[1] = fmaf(pj, bf2f(hv.y), acc[1]);
        acc[2] = fmaf(pj, bf2f(hv.z), acc[2]);
        acc[3] = fmaf(pj, bf2f(hv.w), acc[3]);
      }
    }
    m = mnew;
  }
  float inv = 1.f / ssum;
  size_t o = (size_t)wid * C + FPL * lane;
  if (L1) {
    unsigned short* p = res + o;
    ushort2 rv = *(const ushort2*)p;
    float v0 = fmaxf(acc[0] * inv + bf2f(rv.x), 0.f);  // relu
    float v1 = fmaxf(acc[1] * inv + bf2f(rv.y), 0.f);
    ushort2 ov; ov.x = f2bf(v0); ov.y = f2bf(v1);
    *(ushort2*)p = ov;
  } else {
    ushort4 rv = *(const ushort4*)(res + o);
    float4 ov;
    ov.x = acc[0] * inv + bf2f(rv.x);
    ov.y = acc[1] * inv + bf2f(rv.y);
    ov.z = acc[2] * inv + bf2f(rv.z);
    ov.w = acc[3] * inv + bf2f(rv.w);
    *(float4*)(outf + o) = ov;
  }
}

// ---------------- launch ----------------

extern "C" void kernel_launch(void* const* d_in, const int* in_sizes, int n_in,
                              void* d_out, int out_size, void* d_ws, size_t ws_size,
                              hipStream_t stream) {
  const float* x = (const float*)d_in[0];
  const void* edges = d_in[1];
  const float* W1 = (const float*)d_in[2];
  const float* a_src1 = (const float*)d_in[3];
  const float* a_dst1 = (const float*)d_in[4];
  const float* b1 = (const float*)d_in[5];
  const float* Wres1 = (const float*)d_in[6];
  const float* W2 = (const float*)d_in[7];
  const float* a_src2 = (const float*)d_in[8];
  const float* a_dst2 = (const float*)d_in[9];
  const float* b2 = (const float*)d_in[10];
  const float* Wres2 = (const float*)d_in[11];
  float* out = (float*)d_out;

  int N = in_sizes[0] / 128;
  int E = in_sizes[1] / 2;
  int TOT = E + N;
  int Mpad = (N + 127) & ~127;
  int nblk = (N + 1023) >> 10;

  char* w = (char*)d_ws;
  size_t off = 0;
  auto alloc = [&](size_t bytes) {
    char* p = w + off;
    off += (bytes + 255) & ~(size_t)255;
    return p;
  };
  int* counts = (int*)alloc((size_t)N * 4);
  int* cursor = (int*)alloc((size_t)N * 4);
  int* rowptr = (int*)alloc((size_t)(N + 1) * 4);
  int* bsum = (int*)alloc(1024);
  int* ebsum = (int*)alloc(1024);
  float* as_ = (float*)alloc((size_t)N * 4);
  float* ad_ = (float*)alloc((size_t)N * 4);
  int* src32 = (int*)alloc((size_t)TOT * 4);
  int* dst32 = (int*)alloc((size_t)TOT * 4);
  int* csr = (int*)alloc((size_t)TOT * 4);
  unsigned short* x16 = (unsigned short*)alloc((size_t)Mpad * 128 * 2);
  unsigned short* w1t = (unsigned short*)alloc(128 * 128 * 2);
  unsigned short* wres1t = (unsigned short*)alloc(128 * 128 * 2);
  unsigned short* w2t = (unsigned short*)alloc(256 * 128 * 2);
  unsigned short* wres2t = (unsigned short*)alloc(256 * 128 * 2);
  unsigned short* h16 = (unsigned short*)alloc((size_t)N * 256 * 2);
  unsigned short* out1 = (unsigned short*)alloc((size_t)Mpad * 128 * 2);
  unsigned short* res2 = (unsigned short*)alloc((size_t)Mpad * 256 * 2);

  hipMemsetAsync(counts, 0, (size_t)N * 4, stream);
  hipMemsetAsync(out1 + (size_t)N * 128, 0, (size_t)(Mpad - N) * 128 * 2, stream);

  int gb = (TOT + 255) / 256;
  convert_kernel<<<gb, 256, 0, stream>>>(edges, E, N, src32, dst32, counts);
  scan_partial<<<nblk, 256, 0, stream>>>(counts, bsum, N);
  scan_bsum<<<1, 256, 0, stream>>>(bsum, ebsum, rowptr, nblk, N);
  scan_final<<<nblk, 256, 0, stream>>>(counts, ebsum, rowptr, cursor, N);
  scatter_kernel<<<gb, 256, 0, stream>>>(src32, dst32, cursor, csr, TOT);

  cvt_all<<<(Mpad * 32 + 98304 + 255) / 256, 256, 0, stream>>>(
      x, W1, Wres1, W2, Wres2, x16, w1t, wres1t, w2t, wres2t, N, Mpad);

  int mt = Mpad / 128;
  int sb = (N + 3) / 4;

  // ---- layer 1 (C=128) ----
  hipMemsetAsync(as_, 0, (size_t)N * 4, stream);
  hipMemsetAsync(ad_, 0, (size_t)N * 4, stream);
  gemm_tile<1><<<dim3(mt, 1), 256, 0, stream>>>(x16, w1t, h16, nullptr,
                                                a_src1, a_dst1, as_, ad_, N, 128);
  gemm_tile<0><<<dim3(mt, 1), 256, 0, stream>>>(x16, wres1t, out1, b1,
                                                nullptr, nullptr, nullptr, nullptr, N, 128);
  aggregate_kernel<128, true><<<sb, 256, 0, stream>>>(h16, out1, nullptr, as_, ad_, rowptr, csr, N);

  // ---- layer 2 (C=256) ----
  hipMemsetAsync(as_, 0, (size_t)N * 4, stream);
  hipMemsetAsync(ad_, 0, (size_t)N * 4, stream);
  gemm_tile<1><<<dim3(mt, 2), 256, 0, stream>>>(out1, w2t, h16, nullptr,
                                                a_src2, a_dst2, as_, ad_, N, 256);
  gemm_tile<0><<<dim3(mt, 2), 256, 0, stream>>>(out1, wres2t, res2, b2,
                                                nullptr, nullptr, nullptr, nullptr, N, 256);
  aggregate_kernel<256, false><<<sb, 256, 0, stream>>>(h16, res2, out, as_, ad_, rowptr, csr, N);
}